// Round 1
// baseline (9318.413 us; speedup 1.0000x reference)
//
#include <hip/hip_runtime.h>
#include <math.h>

// Problem constants
constexpr int B = 4, T = 256, D = 1024, H = 16, HD = 64, F = 4096, L = 6, V = 32000;
constexpr float EPS = 1e-6f;
constexpr int MSZ = B * T * D;      // 1,048,576

// flags layout (ints): [0]=do_skip, [1..4]=exited, [5..8]=newly, [9..12]=exl

// ---------------- init ----------------
__global__ void init_kernel(int* flags) {
    int t = threadIdx.x;
    if (t == 0) flags[0] = 0;
    if (t >= 1 && t <= 8) flags[t] = 0;     // exited, newly
    if (t >= 9 && t <= 12) flags[t] = -1;   // exl
}

// ---------------- embedding ----------------
__global__ void embed_kernel(const int* __restrict__ ids, const float* __restrict__ emb,
                             float* __restrict__ x) {
    int row = blockIdx.x;            // b*T + t
    int id = ids[row];
    ((float4*)(x + (size_t)row * D))[threadIdx.x] =
        ((const float4*)(emb + (size_t)id * D))[threadIdx.x];
}

// ---------------- skip decision (reads x BEFORE block) ----------------
__global__ void skip_kernel(const float* __restrict__ x, const float* __restrict__ sw,
                            const float* __restrict__ sb, int* flags, int li) {
    __shared__ float red[256];
    __shared__ float dots[B];
    int tid = threadIdx.x;
    for (int b = 0; b < B; b++) {
        const float* xr = x + ((size_t)(b * T + T - 1)) * D;
        float s = 0.f;
        for (int d = tid; d < D; d += 256) s += xr[d] * sw[d];
        red[tid] = s; __syncthreads();
        for (int off = 128; off > 0; off >>= 1) {
            if (tid < off) red[tid] += red[tid + off];
            __syncthreads();
        }
        if (tid == 0) dots[b] = red[0];
        __syncthreads();
    }
    if (tid == 0) {
        float cnt = 0.f, sum = 0.f;
        for (int b = 0; b < B; b++) {
            float p = 1.f / (1.f + expf(-(dots[b] + sb[li])));
            if (!flags[1 + b]) { cnt += 1.f; sum += p; }
        }
        float mean = sum / fmaxf(cnt, 1.f);
        flags[0] = (li >= 1 && cnt > 0.f && mean < 0.1f) ? 1 : 0;
    }
}

// ---------------- rmsnorm (per row) ----------------
__global__ void rmsnorm_kernel(const float* __restrict__ x, const float* __restrict__ w,
                               float* __restrict__ out, const int* gate) {
    if (gate && *gate) return;
    int row = blockIdx.x;
    const float* xr = x + (size_t)row * D;
    __shared__ float red[256];
    int tid = threadIdx.x;
    float s = 0.f;
    for (int d = tid; d < D; d += 256) { float vv = xr[d]; s += vv * vv; }
    red[tid] = s; __syncthreads();
    for (int off = 128; off > 0; off >>= 1) {
        if (tid < off) red[tid] += red[tid + off];
        __syncthreads();
    }
    float r = rsqrtf(red[0] / (float)D + EPS);
    for (int d = tid; d < D; d += 256) out[(size_t)row * D + d] = xr[d] * w[d] * r;
}

// ---------------- fp32 tiled GEMM: C[M,N] (+)= A[M,K] @ B[K,N] ----------------
__global__ __launch_bounds__(256) void gemm64(const float* __restrict__ A,
                                              const float* __restrict__ Bm,
                                              float* __restrict__ C,
                                              int M, int N, int K, int accFlag,
                                              const int* gate) {
    if (gate && *gate) return;
    __shared__ float As[16][68];   // [k][m], padded (16B-aligned rows)
    __shared__ float Bs[16][64];   // [k][n]
    int tid = threadIdx.x;
    int n0 = blockIdx.x * 64, m0 = blockIdx.y * 64;
    int ty = tid >> 4, tx = tid & 15;
    int arow = tid >> 2, aq = tid & 3;     // A: 64 rows x 4 float4
    int brow = tid >> 6, bcol = tid & 63;  // B: 4 rows/pass x 64 cols
    float acc[4][4] = {};
    for (int k0 = 0; k0 < K; k0 += 16) {
        float4 av = *(const float4*)(A + (size_t)(m0 + arow) * K + k0 + aq * 4);
        As[aq * 4 + 0][arow] = av.x;
        As[aq * 4 + 1][arow] = av.y;
        As[aq * 4 + 2][arow] = av.z;
        As[aq * 4 + 3][arow] = av.w;
#pragma unroll
        for (int r = 0; r < 4; r++)
            Bs[r * 4 + brow][bcol] = Bm[(size_t)(k0 + r * 4 + brow) * N + n0 + bcol];
        __syncthreads();
#pragma unroll
        for (int kk = 0; kk < 16; kk++) {
            float4 a = *(const float4*)&As[kk][ty * 4];
            float4 b = *(const float4*)&Bs[kk][tx * 4];
            acc[0][0] += a.x * b.x; acc[0][1] += a.x * b.y; acc[0][2] += a.x * b.z; acc[0][3] += a.x * b.w;
            acc[1][0] += a.y * b.x; acc[1][1] += a.y * b.y; acc[1][2] += a.y * b.z; acc[1][3] += a.y * b.w;
            acc[2][0] += a.z * b.x; acc[2][1] += a.z * b.y; acc[2][2] += a.z * b.z; acc[2][3] += a.z * b.w;
            acc[3][0] += a.w * b.x; acc[3][1] += a.w * b.y; acc[3][2] += a.w * b.z; acc[3][3] += a.w * b.w;
        }
        __syncthreads();
    }
#pragma unroll
    for (int i = 0; i < 4; i++) {
        float* cp = C + (size_t)(m0 + ty * 4 + i) * N + n0 + tx * 4;
        if (accFlag) {
            float4 old = *(float4*)cp;
            old.x += acc[i][0]; old.y += acc[i][1]; old.z += acc[i][2]; old.w += acc[i][3];
            *(float4*)cp = old;
        } else {
            float4 w4 = { acc[i][0], acc[i][1], acc[i][2], acc[i][3] };
            *(float4*)cp = w4;
        }
    }
}

// ---------------- RoPE on q and k in-place ----------------
__global__ void rope_kernel(float* __restrict__ q, float* __restrict__ k, const int* gate) {
    if (*gate) return;
    int idx = blockIdx.x * 256 + threadIdx.x;   // B*T*H*32 items
    int i = idx & 31; idx >>= 5;
    int h = idx & (H - 1); idx >>= 4;
    int t = idx & (T - 1); idx >>= 8;
    int b = idx;
    float inv = exp2f(-(float)i / 32.f * 13.287712379549449f); // log2(10000)
    float f = (float)t * inv;
    float c = cosf(f), s = sinf(f);
    size_t base = ((size_t)((b * T + t) * H + h)) * HD;
    float q1 = q[base + i], q2 = q[base + 32 + i];
    q[base + i]      = q1 * c - q2 * s;
    q[base + 32 + i] = q1 * s + q2 * c;
    float k1 = k[base + i], k2 = k[base + 32 + i];
    k[base + i]      = k1 * c - k2 * s;
    k[base + 32 + i] = k1 * s + k2 * c;
}

// ---------------- fused attention row: scores -> softmax -> @v ----------------
__global__ __launch_bounds__(256) void attn_kernel(const float* __restrict__ q,
                                                   const float* __restrict__ k,
                                                   const float* __restrict__ v,
                                                   float* __restrict__ o, const int* gate) {
    if (*gate) return;
    int blk = blockIdx.x;            // b*H*T + h*T + tq
    int tq = blk & (T - 1);
    int bh = blk >> 8;
    int h = bh & (H - 1);
    int b = bh >> 4;
    __shared__ float qrow[HD];
    __shared__ float p[T];
    __shared__ float red[256];
    int tid = threadIdx.x;
    if (tid < HD) qrow[tid] = q[((size_t)((b * T + tq) * H + h)) * HD + tid];
    __syncthreads();
    float s;
    if (tid <= tq) {
        const float* kr = k + ((size_t)((b * T + tid) * H + h)) * HD;
        float a = 0.f;
#pragma unroll
        for (int d = 0; d < HD; d++) a += qrow[d] * kr[d];
        s = a * 0.125f;              // 1/sqrt(64)
    } else s = -1e30f;
    red[tid] = s; __syncthreads();
    for (int off = 128; off > 0; off >>= 1) {
        if (tid < off) red[tid] = fmaxf(red[tid], red[tid + off]);
        __syncthreads();
    }
    float m = red[0]; __syncthreads();
    float e = (tid <= tq) ? expf(s - m) : 0.f;
    p[tid] = e;
    red[tid] = e; __syncthreads();
    for (int off = 128; off > 0; off >>= 1) {
        if (tid < off) red[tid] += red[tid + off];
        __syncthreads();
    }
    float invsum = 1.f / red[0];
    __syncthreads();
    int d = tid & 63, part = tid >> 6;
    float acc = 0.f;
    for (int j = part; j < T; j += 4)
        acc += p[j] * v[((size_t)((b * T + j) * H + h)) * HD + d];
    red[tid] = acc; __syncthreads();
    if (tid < 64)
        o[((size_t)((b * T + tq) * H + h)) * HD + d] =
            (red[tid] + red[tid + 64] + red[tid + 128] + red[tid + 192]) * invsum;
}

// ---------------- silu(u) * g -> u ----------------
__global__ void silu_kernel(float* __restrict__ u, const float* __restrict__ g, const int* gate) {
    if (*gate) return;
    int idx = blockIdx.x * 256 + threadIdx.x;   // B*T*F/4 items
    float4 uv = ((float4*)u)[idx];
    float4 gv = ((const float4*)g)[idx];
    uv.x = uv.x / (1.f + expf(-uv.x)) * gv.x;
    uv.y = uv.y / (1.f + expf(-uv.y)) * gv.y;
    uv.z = uv.z / (1.f + expf(-uv.z)) * gv.z;
    uv.w = uv.w / (1.f + expf(-uv.w)) * gv.w;
    ((float4*)u)[idx] = uv;
}

// ---------------- rmsnorm of the last token only -> hl[B,D] ----------------
__global__ void hlast_kernel(const float* __restrict__ x, const float* __restrict__ fn,
                             float* __restrict__ hl, const int* gate) {
    if (*gate) return;
    int b = blockIdx.x;
    const float* xr = x + ((size_t)(b * T + T - 1)) * D;
    __shared__ float red[256];
    int tid = threadIdx.x;
    float s = 0.f;
    for (int d = tid; d < D; d += 256) { float vv = xr[d]; s += vv * vv; }
    red[tid] = s; __syncthreads();
    for (int off = 128; off > 0; off >>= 1) {
        if (tid < off) red[tid] += red[tid + off];
        __syncthreads();
    }
    float r = rsqrtf(red[0] / (float)D + EPS);
    for (int d = tid; d < D; d += 256) hl[b * D + d] = xr[d] * fn[d] * r;
}

// ---------------- last-token logits: per-block online-softmax partials ----------------
// grid 125 x 256 => one v per thread. partial[(blk*B+b)*2+{0,1}] = (max, sumexp)
__global__ __launch_bounds__(256) void logits_partial_kernel(const float* __restrict__ hl,
                                                             const float* __restrict__ lm,
                                                             float* __restrict__ partial,
                                                             const int* gate) {
    if (*gate) return;
    __shared__ float hls[B * D];    // 16 KB
    int tid = threadIdx.x;
    for (int i = tid; i < B * D; i += 256) hls[i] = hl[i];
    __syncthreads();
    int v0 = blockIdx.x * 256 + tid;
    float a0 = 0.f, a1 = 0.f, a2 = 0.f, a3 = 0.f;
    for (int d = 0; d < D; d++) {
        float w = lm[(size_t)d * V + v0];
        a0 += hls[d] * w;
        a1 += hls[D + d] * w;
        a2 += hls[2 * D + d] * w;
        a3 += hls[3 * D + d] * w;
    }
    float l[B] = { a0, a1, a2, a3 };
    __shared__ float rm[256], rs[256];
    for (int b = 0; b < B; b++) {
        rm[tid] = l[b]; rs[tid] = 1.f; __syncthreads();
        for (int off = 128; off > 0; off >>= 1) {
            if (tid < off) {
                float m1 = rm[tid], s1 = rs[tid], m2 = rm[tid + off], s2 = rs[tid + off];
                float mm = fmaxf(m1, m2);
                rs[tid] = s1 * expf(m1 - mm) + s2 * expf(m2 - mm);
                rm[tid] = mm;
            }
            __syncthreads();
        }
        if (tid == 0) {
            partial[((size_t)blockIdx.x * B + b) * 2]     = rm[0];
            partial[((size_t)blockIdx.x * B + b) * 2 + 1] = rs[0];
        }
        __syncthreads();
    }
}

// ---------------- exit decision ----------------
__global__ void decide_kernel(const float* __restrict__ x, const float* __restrict__ ew,
                              const float* __restrict__ eb, const float* __restrict__ partial,
                              int* flags, int li) {
    __shared__ float red[256];
    __shared__ float dots[B];
    int tid = threadIdx.x;
    int doSkip = flags[0];
    for (int b = 0; b < B; b++) {
        const float* xr = x + ((size_t)(b * T + T - 1)) * D;
        float s = 0.f;
        for (int d = tid; d < D; d += 256) s += xr[d] * ew[d];
        red[tid] = s; __syncthreads();
        for (int off = 128; off > 0; off >>= 1) {
            if (tid < off) red[tid] += red[tid + off];
            __syncthreads();
        }
        if (tid == 0) dots[b] = red[0];
        __syncthreads();
    }
    if (tid == 0) {
        for (int b = 0; b < B; b++) {
            int newly = 0;
            if (!doSkip) {
                float m = -1e30f, s = 0.f;
                for (int g = 0; g < 125; g++) {
                    float mg = partial[((size_t)g * B + b) * 2];
                    float sg = partial[((size_t)g * B + b) * 2 + 1];
                    float mn = fmaxf(m, mg);
                    s = s * expf(m - mn) + sg * expf(mg - mn);
                    m = mn;
                }
                float conf = 1.f / s;                 // max softmax prob
                float ep = 1.f / (1.f + expf(-(dots[b] + eb[li])));
                int should = (conf > 0.9f) || (ep > 0.9f);
                if (should && !flags[1 + b]) newly = 1;   // li >= MIN_LAYERS-1 always true
            }
            flags[5 + b] = newly;
            if (newly) { flags[1 + b] = 1; flags[9 + b] = li; }
        }
    }
}

// ---------------- capture x snapshot for newly-exited batches ----------------
__global__ void capture_kernel(const float* __restrict__ x, float* __restrict__ xcap,
                               const int* flags) {
    int row = blockIdx.x;           // b*T + t
    int b = row >> 8;               // / T
    if (!flags[5 + b]) return;
    ((float4*)(xcap + (size_t)row * D))[threadIdx.x] =
        ((const float4*)(x + (size_t)row * D))[threadIdx.x];
}

// ---------------- finalize: never-exited batches take final x, exl=L-1 ----------------
__global__ void finalize_kernel(const float* __restrict__ x, float* __restrict__ xcap,
                                int* flags) {
    int row = blockIdx.x;
    int b = row >> 8;
    if (flags[1 + b]) return;
    ((float4*)(xcap + (size_t)row * D))[threadIdx.x] =
        ((const float4*)(x + (size_t)row * D))[threadIdx.x];
    if ((row & (T - 1)) == 0 && threadIdx.x == 0) flags[9 + b] = L - 1;
}

// ---------------- write exl as floats after the logits ----------------
__global__ void writeexl_kernel(float* __restrict__ out, const int* flags) {
    int b = threadIdx.x;
    if (b < B) out[(size_t)B * T * V + b] = (float)flags[9 + b];
}

extern "C" void kernel_launch(void* const* d_in, const int* in_sizes, int n_in,
                              void* d_out, int out_size, void* d_ws, size_t ws_size,
                              hipStream_t stream) {
    const int*   ids = (const int*)d_in[0];
    const float* emb = (const float*)d_in[1];
    const float* wq  = (const float*)d_in[2];
    const float* wk  = (const float*)d_in[3];
    const float* wv  = (const float*)d_in[4];
    const float* wo  = (const float*)d_in[5];
    const float* w1  = (const float*)d_in[6];
    const float* w2  = (const float*)d_in[7];
    const float* w3  = (const float*)d_in[8];
    const float* n1  = (const float*)d_in[9];
    const float* n2  = (const float*)d_in[10];
    const float* fn  = (const float*)d_in[11];
    const float* lm  = (const float*)d_in[12];
    const float* exw = (const float*)d_in[13];
    const float* exb = (const float*)d_in[14];
    const float* skw = (const float*)d_in[15];
    const float* skb = (const float*)d_in[16];

    float* ws   = (float*)d_ws;
    float* xB   = ws;                 // [B*T*D]
    float* hB   = ws + 1 * (size_t)MSZ;
    float* qB   = ws + 2 * (size_t)MSZ;
    float* kB   = ws + 3 * (size_t)MSZ;
    float* vB   = ws + 4 * (size_t)MSZ;
    float* oB   = ws + 5 * (size_t)MSZ;
    float* uB   = ws + 6 * (size_t)MSZ;   // [B*T*F] = 4*MSZ
    float* gB   = ws + 10 * (size_t)MSZ;  // [B*T*F]
    float* xcap = ws + 14 * (size_t)MSZ;
    float* hfin = ws + 15 * (size_t)MSZ;
    float* hl   = ws + 16 * (size_t)MSZ;        // [B*D]
    float* part = ws + 16 * (size_t)MSZ + 4096; // [125*B*2]
    int*  flags = (int*)(ws + 16 * (size_t)MSZ + 8192);

    init_kernel<<<1, 64, 0, stream>>>(flags);
    embed_kernel<<<B * T, 256, 0, stream>>>(ids, emb, xB);

    dim3 g1(16, 16);   // N=1024
    dim3 g2(64, 16);   // N=4096
    for (int li = 0; li < L; li++) {
        const int* gate = flags;
        skip_kernel<<<1, 256, 0, stream>>>(xB, skw + (size_t)li * D, skb, flags, li);
        rmsnorm_kernel<<<B * T, 256, 0, stream>>>(xB, n1 + (size_t)li * D, hB, gate);
        gemm64<<<g1, 256, 0, stream>>>(hB, wq + (size_t)li * D * D, qB, B * T, D, D, 0, gate);
        gemm64<<<g1, 256, 0, stream>>>(hB, wk + (size_t)li * D * D, kB, B * T, D, D, 0, gate);
        gemm64<<<g1, 256, 0, stream>>>(hB, wv + (size_t)li * D * D, vB, B * T, D, D, 0, gate);
        rope_kernel<<<(B * T * H * 32) / 256, 256, 0, stream>>>(qB, kB, gate);
        attn_kernel<<<B * H * T, 256, 0, stream>>>(qB, kB, vB, oB, gate);
        gemm64<<<g1, 256, 0, stream>>>(oB, wo + (size_t)li * D * D, xB, B * T, D, D, 1, gate);
        rmsnorm_kernel<<<B * T, 256, 0, stream>>>(xB, n2 + (size_t)li * D, hB, gate);
        gemm64<<<g2, 256, 0, stream>>>(hB, w1 + (size_t)li * D * F, uB, B * T, F, D, 0, gate);
        gemm64<<<g2, 256, 0, stream>>>(hB, w3 + (size_t)li * D * F, gB, B * T, F, D, 0, gate);
        silu_kernel<<<(B * T * F / 4) / 256, 256, 0, stream>>>(uB, gB, gate);
        gemm64<<<g1, 256, 0, stream>>>(uB, w2 + (size_t)li * F * D, xB, B * T, D, F, 1, gate);
        hlast_kernel<<<B, 256, 0, stream>>>(xB, fn, hl, gate);
        logits_partial_kernel<<<125, 256, 0, stream>>>(hl, lm, part, gate);
        decide_kernel<<<1, 256, 0, stream>>>(xB, exw + (size_t)li * D, exb, part, flags, li);
        capture_kernel<<<B * T, 256, 0, stream>>>(xB, xcap, flags);
    }
    finalize_kernel<<<B * T, 256, 0, stream>>>(xB, xcap, flags);
    rmsnorm_kernel<<<B * T, 256, 0, stream>>>(xcap, fn, hfin, nullptr);
    dim3 gf(V / 64, 16);   // 500 x 16
    gemm64<<<gf, 256, 0, stream>>>(hfin, lm, (float*)d_out, B * T, V, D, 0, nullptr);
    writeexl_kernel<<<1, 64, 0, stream>>>((float*)d_out, flags);
}

// Round 2
// 4307.296 us; speedup vs baseline: 2.1634x; 2.1634x over previous
//
#include <hip/hip_runtime.h>
#include <hip/hip_bf16.h>
#include <math.h>

// Problem constants
constexpr int B = 4, T = 256, D = 1024, H = 16, HD = 64, F = 4096, L = 6, V = 32000;
constexpr float EPS = 1e-6f;
constexpr int M_ROWS = B * T;     // 1024

typedef __hip_bfloat16 bf16;
typedef __bf16  bf16x8 __attribute__((ext_vector_type(8)));
typedef float   f32x4  __attribute__((ext_vector_type(4)));

// flags layout (ints): [0]=do_skip, [1..4]=exited, [5..8]=newly, [9..12]=exl

__device__ inline void async_copy16(const void* g, void* l) {
    __builtin_amdgcn_global_load_lds(
        (const __attribute__((address_space(1))) void*)g,
        (__attribute__((address_space(3))) void*)l, 16, 0, 0);
}

// ---------------- init ----------------
__global__ void init_kernel(int* flags) {
    int t = threadIdx.x;
    if (t == 0) flags[0] = 0;
    if (t >= 1 && t <= 8) flags[t] = 0;
    if (t >= 9 && t <= 12) flags[t] = -1;
}

// ---------------- embedding ----------------
__global__ void embed_kernel(const int* __restrict__ ids, const float* __restrict__ emb,
                             float* __restrict__ x) {
    int row = blockIdx.x;
    int id = ids[row];
    ((float4*)(x + (size_t)row * D))[threadIdx.x] =
        ((const float4*)(emb + (size_t)id * D))[threadIdx.x];
}

// ---------------- transpose-convert fp32 [K][NS] -> bf16 [n*rs+ro][K] ----------------
__global__ __launch_bounds__(256) void convtrans_kernel(const float* __restrict__ src,
                                                        bf16* __restrict__ dst,
                                                        int K, int NS, int rs, int ro) {
    __shared__ float tile[64][65];
    int tid = threadIdx.x;
    int k0 = blockIdx.y * 64, n0 = blockIdx.x * 64;
    int cr = tid >> 6, cc = tid & 63;
#pragma unroll
    for (int p = 0; p < 16; p++)
        tile[p * 4 + cr][cc] = src[(size_t)(k0 + p * 4 + cr) * NS + n0 + cc];
    __syncthreads();
    int n = tid >> 4, k4 = (tid & 15) * 4;
#pragma unroll
    for (int p = 0; p < 4; p++) {
        int nn = p * 16 + n;
        union { ushort4 u4; bf16 h[4]; } cv;
        cv.h[0] = __float2bfloat16(tile[k4 + 0][nn]);
        cv.h[1] = __float2bfloat16(tile[k4 + 1][nn]);
        cv.h[2] = __float2bfloat16(tile[k4 + 2][nn]);
        cv.h[3] = __float2bfloat16(tile[k4 + 3][nn]);
        *(ushort4*)(dst + ((size_t)(n0 + nn) * rs + ro) * K + k0 + k4) = cv.u4;
    }
}

// ---------------- MFMA GEMM: C[M][ldc] (+)= A[M][K](bf16) @ BT[N][K](bf16)^T ----------------
// MODE 0: store fp32   MODE 1: accumulate fp32   MODE 2: silu-pair -> bf16 Cb[M][ldc/2]
template<int MODE>
__global__ __launch_bounds__(256) void gemm_mfma(const bf16* __restrict__ A,
                                                 const bf16* __restrict__ BT,
                                                 float* __restrict__ C,
                                                 bf16* __restrict__ Cb,
                                                 int K, int ldc, const int* gate) {
    if (gate && *gate) return;
    __shared__ bf16 As[128 * 32];
    __shared__ bf16 Bs[128 * 32];
    int tid = threadIdx.x;
    int wave = tid >> 6, lane = tid & 63;
    int m0 = blockIdx.y * 128, n0 = blockIdx.x * 128;
    int srow = lane >> 2, scol = (lane & 3) * 8;
    int wm = wave >> 1, wn = wave & 1;
    int rowbase = wm * 64, colbase = wn * 64;
    int fm = lane & 15, quad = lane >> 4;
    f32x4 acc[4][4] = {};
    for (int k0 = 0; k0 < K; k0 += 32) {
#pragma unroll
        for (int r = 0; r < 2; r++) {
            int c = wave * 2 + r;
            int arow = c * 16 + srow;
            async_copy16(A + (size_t)(m0 + arow) * K + k0 + scol, &As[c * 512 + lane * 8]);
            async_copy16(BT + (size_t)(n0 + arow) * K + k0 + scol, &Bs[c * 512 + lane * 8]);
        }
        __syncthreads();
        bf16x8 af[4], bfr[4];
#pragma unroll
        for (int i = 0; i < 4; i++)
            af[i] = *(const bf16x8*)&As[(rowbase + i * 16 + fm) * 32 + quad * 8];
#pragma unroll
        for (int j = 0; j < 4; j++)
            bfr[j] = *(const bf16x8*)&Bs[(colbase + j * 16 + fm) * 32 + quad * 8];
#pragma unroll
        for (int i = 0; i < 4; i++)
#pragma unroll
            for (int j = 0; j < 4; j++)
                acc[i][j] = __builtin_amdgcn_mfma_f32_16x16x32_bf16(af[i], bfr[j], acc[i][j], 0, 0, 0);
        __syncthreads();
    }
#pragma unroll
    for (int i = 0; i < 4; i++) {
        int row = m0 + rowbase + i * 16 + quad * 4;
#pragma unroll
        for (int j = 0; j < 4; j++) {
            int col = n0 + colbase + j * 16 + fm;
#pragma unroll
            for (int r = 0; r < 4; r++) {
                float vv = acc[i][j][r];
                if (MODE == 0) {
                    C[(size_t)(row + r) * ldc + col] = vv;
                } else if (MODE == 1) {
                    C[(size_t)(row + r) * ldc + col] += vv;
                } else {
                    float g = __shfl_xor(vv, 1, 64);   // neighbor holds the w3 (odd-col) value
                    if ((lane & 1) == 0) {
                        float s = vv / (1.f + expf(-vv)) * g;
                        Cb[(size_t)(row + r) * (ldc >> 1) + (col >> 1)] = __float2bfloat16(s);
                    }
                }
            }
        }
    }
}

// ---------------- skip decision (x BEFORE block) ----------------
__global__ void skip_kernel(const float* __restrict__ x, const float* __restrict__ sw,
                            const float* __restrict__ sb, int* flags, int li) {
    __shared__ float red[256];
    __shared__ float dots[B];
    int tid = threadIdx.x;
    for (int b = 0; b < B; b++) {
        const float* xr = x + ((size_t)(b * T + T - 1)) * D;
        float s = 0.f;
        for (int d = tid; d < D; d += 256) s += xr[d] * sw[d];
        red[tid] = s; __syncthreads();
        for (int off = 128; off > 0; off >>= 1) {
            if (tid < off) red[tid] += red[tid + off];
            __syncthreads();
        }
        if (tid == 0) dots[b] = red[0];
        __syncthreads();
    }
    if (tid == 0) {
        float cnt = 0.f, sum = 0.f;
        for (int b = 0; b < B; b++) {
            float p = 1.f / (1.f + expf(-(dots[b] + sb[li])));
            if (!flags[1 + b]) { cnt += 1.f; sum += p; }
        }
        float mean = sum / fmaxf(cnt, 1.f);
        flags[0] = (li >= 1 && cnt > 0.f && mean < 0.1f) ? 1 : 0;
    }
}

// ---------------- rmsnorm -> bf16 ----------------
__global__ void rmsnorm_bf16_kernel(const float* __restrict__ x, const float* __restrict__ w,
                                    bf16* __restrict__ out, const int* gate) {
    if (gate && *gate) return;
    int row = blockIdx.x;
    const float* xr = x + (size_t)row * D;
    __shared__ float red[256];
    int tid = threadIdx.x;
    float s = 0.f;
    for (int d = tid; d < D; d += 256) { float vv = xr[d]; s += vv * vv; }
    red[tid] = s; __syncthreads();
    for (int off = 128; off > 0; off >>= 1) {
        if (tid < off) red[tid] += red[tid + off];
        __syncthreads();
    }
    float r = rsqrtf(red[0] / (float)D + EPS);
    for (int d = tid; d < D; d += 256)
        out[(size_t)row * D + d] = __float2bfloat16(xr[d] * w[d] * r);
}

// ---------------- RoPE on fused qkv fp32 buffer ----------------
__global__ void rope_kernel(float* __restrict__ qkv, const int* gate) {
    if (*gate) return;
    int idx = blockIdx.x * 256 + threadIdx.x;   // B*T*H*32 items
    int i = idx & 31; idx >>= 5;
    int h = idx & (H - 1); idx >>= 4;
    int t = idx & (T - 1); idx >>= 8;
    int b = idx;
    float inv = exp2f(-(float)i / 32.f * 13.287712379549449f);
    float f = (float)t * inv;
    float c = cosf(f), s = sinf(f);
    size_t base = (size_t)(b * T + t) * 3072 + h * 64;
    float q1 = qkv[base + i], q2 = qkv[base + 32 + i];
    qkv[base + i]      = q1 * c - q2 * s;
    qkv[base + 32 + i] = q1 * s + q2 * c;
    size_t kb = base + 1024;
    float k1 = qkv[kb + i], k2 = qkv[kb + 32 + i];
    qkv[kb + i]      = k1 * c - k2 * s;
    qkv[kb + 32 + i] = k1 * s + k2 * c;
}

// ---------------- fused attention row -> bf16 output ----------------
__global__ __launch_bounds__(256) void attn_kernel(const float* __restrict__ qkv,
                                                   bf16* __restrict__ o, const int* gate) {
    if (*gate) return;
    int blk = blockIdx.x;
    int tq = blk & (T - 1);
    int bh = blk >> 8;
    int h = bh & (H - 1);
    int b = bh >> 4;
    __shared__ float qrow[HD];
    __shared__ float p[T];
    __shared__ float red[256];
    int tid = threadIdx.x;
    if (tid < HD) qrow[tid] = qkv[(size_t)(b * T + tq) * 3072 + h * 64 + tid];
    __syncthreads();
    float s;
    if (tid <= tq) {
        const float* kr = qkv + (size_t)(b * T + tid) * 3072 + 1024 + h * 64;
        float a = 0.f;
#pragma unroll
        for (int d = 0; d < HD; d++) a += qrow[d] * kr[d];
        s = a * 0.125f;
    } else s = -1e30f;
    red[tid] = s; __syncthreads();
    for (int off = 128; off > 0; off >>= 1) {
        if (tid < off) red[tid] = fmaxf(red[tid], red[tid + off]);
        __syncthreads();
    }
    float m = red[0]; __syncthreads();
    float e = (tid <= tq) ? expf(s - m) : 0.f;
    p[tid] = e;
    red[tid] = e; __syncthreads();
    for (int off = 128; off > 0; off >>= 1) {
        if (tid < off) red[tid] += red[tid + off];
        __syncthreads();
    }
    float invsum = 1.f / red[0];
    __syncthreads();
    int d = tid & 63, part = tid >> 6;
    float acc = 0.f;
    for (int j = part; j < T; j += 4)
        acc += p[j] * qkv[(size_t)(b * T + j) * 3072 + 2048 + h * 64 + d];
    red[tid] = acc; __syncthreads();
    if (tid < 64)
        o[(size_t)(b * T + tq) * 1024 + h * 64 + d] =
            __float2bfloat16((red[tid] + red[tid + 64] + red[tid + 128] + red[tid + 192]) * invsum);
}

// ---------------- rmsnorm of last token only -> fp32 hl[B,D] ----------------
__global__ void hlast_kernel(const float* __restrict__ x, const float* __restrict__ fn,
                             float* __restrict__ hl, const int* gate) {
    if (*gate) return;
    int b = blockIdx.x;
    const float* xr = x + ((size_t)(b * T + T - 1)) * D;
    __shared__ float red[256];
    int tid = threadIdx.x;
    float s = 0.f;
    for (int d = tid; d < D; d += 256) { float vv = xr[d]; s += vv * vv; }
    red[tid] = s; __syncthreads();
    for (int off = 128; off > 0; off >>= 1) {
        if (tid < off) red[tid] += red[tid + off];
        __syncthreads();
    }
    float r = rsqrtf(red[0] / (float)D + EPS);
    for (int d = tid; d < D; d += 256) hl[b * D + d] = xr[d] * fn[d] * r;
}

// ---------------- last-token logits partials (fp32 lm_head, online softmax) ----------------
__global__ __launch_bounds__(256) void logits_partial_kernel(const float* __restrict__ hl,
                                                             const float* __restrict__ lm,
                                                             float* __restrict__ partial,
                                                             const int* gate) {
    if (*gate) return;
    __shared__ float hls[B * D];
    int tid = threadIdx.x;
    for (int i = tid; i < B * D; i += 256) hls[i] = hl[i];
    __syncthreads();
    int v0 = blockIdx.x * 256 + tid;
    float a0 = 0.f, a1 = 0.f, a2 = 0.f, a3 = 0.f;
    for (int d = 0; d < D; d++) {
        float w = lm[(size_t)d * V + v0];
        a0 += hls[d] * w;
        a1 += hls[D + d] * w;
        a2 += hls[2 * D + d] * w;
        a3 += hls[3 * D + d] * w;
    }
    float l[B] = { a0, a1, a2, a3 };
    __shared__ float rm[256], rs[256];
    for (int b = 0; b < B; b++) {
        rm[tid] = l[b]; rs[tid] = 1.f; __syncthreads();
        for (int off = 128; off > 0; off >>= 1) {
            if (tid < off) {
                float m1 = rm[tid], s1 = rs[tid], m2 = rm[tid + off], s2 = rs[tid + off];
                float mm = fmaxf(m1, m2);
                rs[tid] = s1 * expf(m1 - mm) + s2 * expf(m2 - mm);
                rm[tid] = mm;
            }
            __syncthreads();
        }
        if (tid == 0) {
            partial[((size_t)blockIdx.x * B + b) * 2]     = rm[0];
            partial[((size_t)blockIdx.x * B + b) * 2 + 1] = rs[0];
        }
        __syncthreads();
    }
}

// ---------------- exit decision ----------------
__global__ void decide_kernel(const float* __restrict__ x, const float* __restrict__ ew,
                              const float* __restrict__ eb, const float* __restrict__ partial,
                              int* flags, int li) {
    __shared__ float red[256];
    __shared__ float dots[B];
    int tid = threadIdx.x;
    int doSkip = flags[0];
    for (int b = 0; b < B; b++) {
        const float* xr = x + ((size_t)(b * T + T - 1)) * D;
        float s = 0.f;
        for (int d = tid; d < D; d += 256) s += xr[d] * ew[d];
        red[tid] = s; __syncthreads();
        for (int off = 128; off > 0; off >>= 1) {
            if (tid < off) red[tid] += red[tid + off];
            __syncthreads();
        }
        if (tid == 0) dots[b] = red[0];
        __syncthreads();
    }
    if (tid == 0) {
        for (int b = 0; b < B; b++) {
            int newly = 0;
            if (!doSkip) {
                float m = -1e30f, s = 0.f;
                for (int g = 0; g < 125; g++) {
                    float mg = partial[((size_t)g * B + b) * 2];
                    float sg = partial[((size_t)g * B + b) * 2 + 1];
                    float mn = fmaxf(m, mg);
                    s = s * expf(m - mn) + sg * expf(mg - mn);
                    m = mn;
                }
                float conf = 1.f / s;
                float ep = 1.f / (1.f + expf(-(dots[b] + eb[li])));
                int should = (conf > 0.9f) || (ep > 0.9f);
                if (should && !flags[1 + b]) newly = 1;
            }
            flags[5 + b] = newly;
            if (newly) { flags[1 + b] = 1; flags[9 + b] = li; }
        }
    }
}

// ---------------- capture x for newly-exited batches ----------------
__global__ void capture_kernel(const float* __restrict__ x, float* __restrict__ xcap,
                               const int* flags) {
    int row = blockIdx.x;
    int b = row >> 8;
    if (!flags[5 + b]) return;
    ((float4*)(xcap + (size_t)row * D))[threadIdx.x] =
        ((const float4*)(x + (size_t)row * D))[threadIdx.x];
}

// ---------------- finalize never-exited batches ----------------
__global__ void finalize_kernel(const float* __restrict__ x, float* __restrict__ xcap,
                                int* flags) {
    int row = blockIdx.x;
    int b = row >> 8;
    if (flags[1 + b]) return;
    ((float4*)(xcap + (size_t)row * D))[threadIdx.x] =
        ((const float4*)(x + (size_t)row * D))[threadIdx.x];
    if ((row & (T - 1)) == 0 && threadIdx.x == 0) flags[9 + b] = L - 1;
}

// ---------------- write exl as floats after logits ----------------
__global__ void writeexl_kernel(float* __restrict__ out, const int* flags) {
    int b = threadIdx.x;
    if (b < B) out[(size_t)B * T * V + b] = (float)flags[9 + b];
}

extern "C" void kernel_launch(void* const* d_in, const int* in_sizes, int n_in,
                              void* d_out, int out_size, void* d_ws, size_t ws_size,
                              hipStream_t stream) {
    const int*   ids = (const int*)d_in[0];
    const float* emb = (const float*)d_in[1];
    const float* wq  = (const float*)d_in[2];
    const float* wk  = (const float*)d_in[3];
    const float* wv  = (const float*)d_in[4];
    const float* wo  = (const float*)d_in[5];
    const float* w1  = (const float*)d_in[6];
    const float* w2  = (const float*)d_in[7];
    const float* w3  = (const float*)d_in[8];
    const float* n1  = (const float*)d_in[9];
    const float* n2  = (const float*)d_in[10];
    const float* fn  = (const float*)d_in[11];
    const float* lm  = (const float*)d_in[12];
    const float* exw = (const float*)d_in[13];
    const float* exb = (const float*)d_in[14];
    const float* skw = (const float*)d_in[15];
    const float* skb = (const float*)d_in[16];

    char* base = (char*)d_ws;
    float* xB    = (float*)(base + 0x00000000);          // 4 MB
    float* qkvB  = (float*)(base + 0x00400000);          // 12 MB fp32 [M][3072]
    float* xcap  = (float*)(base + 0x01000000);          // 4 MB
    bf16*  a2B   = (bf16*) (base + 0x01400000);          // 8 MB  [M][4096]
    bf16*  wqkvT = (bf16*) (base + 0x01C00000);          // 6 MB  [3072][1024]
    bf16*  w13T  = (bf16*) (base + 0x02200000);          // 16 MB [8192][1024] interleaved u/g
    bf16*  w2T   = (bf16*) (base + 0x03200000);          // 8 MB  [1024][4096]
    bf16*  woT   = (bf16*) (base + 0x03A00000);          // 2 MB  [1024][1024]
    bf16*  hB    = (bf16*) (base + 0x03C00000);          // 2 MB  [M][1024]
    bf16*  oB    = (bf16*) (base + 0x03E00000);          // 2 MB  [M][1024]
    bf16*  hfin  = (bf16*) (base + 0x04000000);          // 2 MB  [M][1024]
    bf16*  lmTc  = (bf16*) (base + 0x04200000);          // 6.25 MB [3200][1024]
    float* hl    = (float*)(base + 0x04900000);          // 16 KB
    float* part  = (float*)(base + 0x04904000);          // 4 KB
    int*   flags = (int*)  (base + 0x04905000);

    init_kernel<<<1, 64, 0, stream>>>(flags);
    embed_kernel<<<M_ROWS, 256, 0, stream>>>(ids, emb, xB);

    for (int li = 0; li < L; li++) {
        const int* gate = flags;
        size_t wOffDD = (size_t)li * D * D;
        size_t wOffDF = (size_t)li * D * F;
        // weight conversions (transposed bf16, per-layer buffers)
        convtrans_kernel<<<dim3(16, 16), 256, 0, stream>>>(wq + wOffDD, wqkvT, 1024, 1024, 1, 0);
        convtrans_kernel<<<dim3(16, 16), 256, 0, stream>>>(wk + wOffDD, wqkvT, 1024, 1024, 1, 1024);
        convtrans_kernel<<<dim3(16, 16), 256, 0, stream>>>(wv + wOffDD, wqkvT, 1024, 1024, 1, 2048);
        convtrans_kernel<<<dim3(16, 16), 256, 0, stream>>>(wo + wOffDD, woT,   1024, 1024, 1, 0);
        convtrans_kernel<<<dim3(64, 16), 256, 0, stream>>>(w1 + wOffDF, w13T,  1024, 4096, 2, 0);
        convtrans_kernel<<<dim3(64, 16), 256, 0, stream>>>(w3 + wOffDF, w13T,  1024, 4096, 2, 1);
        convtrans_kernel<<<dim3(16, 64), 256, 0, stream>>>(w2 + wOffDF, w2T,   4096, 1024, 1, 0);

        skip_kernel<<<1, 256, 0, stream>>>(xB, skw + (size_t)li * D, skb, flags, li);
        rmsnorm_bf16_kernel<<<M_ROWS, 256, 0, stream>>>(xB, n1 + (size_t)li * D, hB, gate);
        gemm_mfma<0><<<dim3(24, 8), 256, 0, stream>>>(hB, wqkvT, qkvB, nullptr, 1024, 3072, gate);
        rope_kernel<<<(B * T * H * 32) / 256, 256, 0, stream>>>(qkvB, gate);
        attn_kernel<<<B * H * T, 256, 0, stream>>>(qkvB, oB, gate);
        gemm_mfma<1><<<dim3(8, 8), 256, 0, stream>>>(oB, woT, xB, nullptr, 1024, 1024, gate);
        rmsnorm_bf16_kernel<<<M_ROWS, 256, 0, stream>>>(xB, n2 + (size_t)li * D, hB, gate);
        gemm_mfma<2><<<dim3(64, 8), 256, 0, stream>>>(hB, w13T, nullptr, a2B, 1024, 8192, gate);
        gemm_mfma<1><<<dim3(8, 8), 256, 0, stream>>>(a2B, w2T, xB, nullptr, 4096, 1024, gate);

        hlast_kernel<<<B, 256, 0, stream>>>(xB, fn, hl, gate);
        logits_partial_kernel<<<125, 256, 0, stream>>>(hl, lm, part, gate);
        decide_kernel<<<1, 256, 0, stream>>>(xB, exw + (size_t)li * D, exb, part, flags, li);
        capture_kernel<<<M_ROWS, 256, 0, stream>>>(xB, xcap, flags);
    }

    finalize_kernel<<<M_ROWS, 256, 0, stream>>>(xB, xcap, flags);
    rmsnorm_bf16_kernel<<<M_ROWS, 256, 0, stream>>>(xcap, fn, hfin, nullptr);
    // final logits: 10 chunks of 3200 cols, transpose-convert lm chunk then MFMA GEMM
    for (int c = 0; c < 10; c++) {
        convtrans_kernel<<<dim3(50, 16), 256, 0, stream>>>(lm + c * 3200, lmTc, 1024, V, 1, 0);
        gemm_mfma<0><<<dim3(25, 8), 256, 0, stream>>>(hfin, lmTc, (float*)d_out + c * 3200,
                                                      nullptr, 1024, V, nullptr);
    }
    writeexl_kernel<<<1, 64, 0, stream>>>((float*)d_out, flags);
}